// Round 1
// baseline (196.646 us; speedup 1.0000x reference)
//
#include <hip/hip_runtime.h>

typedef __bf16 bf16;
typedef __attribute__((ext_vector_type(8))) __bf16 bf16x8;
typedef __attribute__((ext_vector_type(4))) float f32x4;

#define DEV __device__ __forceinline__

DEV f32x4 mfma16(bf16x8 a, bf16x8 b, f32x4 c) {
  return __builtin_amdgcn_mfma_f32_16x16x32_bf16(a, b, c, 0, 0, 0);
}

// async global->LDS, 16B per lane; LDS dest must be wave-linear (base + lane*16)
DEV void gll16(const bf16* g, bf16* l) {
  __builtin_amdgcn_global_load_lds(
      (const __attribute__((address_space(1))) void*)g,
      (__attribute__((address_space(3))) void*)l, 16, 0, 0);
}

// ---------------- prep kernels ----------------
__global__ void cast_bf16_k(const float* __restrict__ in, bf16* __restrict__ out, int n) {
  for (int i = blockIdx.x * blockDim.x + threadIdx.x; i < n; i += gridDim.x * blockDim.x)
    out[i] = (bf16)in[i];
}

// in fp32 [Bn][R][C] -> out bf16 [Bn][C][R]
__global__ void transpose_cast_k(const float* __restrict__ in, bf16* __restrict__ out,
                                 int Bn, int R, int C) {
  int total = Bn * R * C;
  for (int i = blockIdx.x * blockDim.x + threadIdx.x; i < total; i += gridDim.x * blockDim.x) {
    int b = i / (R * C);
    int rem = i - b * R * C;
    int r = rem / C, c = rem - r * C;
    out[(size_t)b * R * C + (size_t)c * R + r] = (bf16)in[i];
  }
}

// ---------------- 64x64 tile GEMM: C[M][N] = A[M][K] * Bt[N][K]^T + bias ----------------
// EPI 0: fp32 out = acc+bias ; EPI 1: bf16 out = relu(acc+bias)
template <int EPI>
__global__ __launch_bounds__(256) void gemm64(
    const bf16* __restrict__ A, const bf16* __restrict__ Bt,
    const float* __restrict__ bias, float* __restrict__ outf,
    bf16* __restrict__ outb, int M, int N, int K) {
  __shared__ bf16 As[64 * 64];
  __shared__ bf16 Bs[64 * 64];
  const int tid = threadIdx.x;
  const int w = tid >> 6, l = tid & 63;
  const int lh = l & 15, lg = l >> 4;
  const int m0 = blockIdx.x * 64, n0 = blockIdx.y * 64;
  const int mb = (w & 1) * 32, nb = (w >> 1) * 32;
  f32x4 acc[2][2] = {};
  for (int kt = 0; kt < K; kt += 64) {
    __syncthreads();
#pragma unroll
    for (int p = 0; p < 2; ++p) {
      int c = p * 256 + tid;
      int r = c >> 3, cc = c & 7;
      int kk = kt + ((cc ^ (r & 7)) << 3);  // XOR-swizzle the SOURCE, LDS stays linear
      gll16(A + (size_t)(m0 + r) * K + kk, As + c * 8);
      gll16(Bt + (size_t)(n0 + r) * K + kk, Bs + c * 8);
    }
    __syncthreads();
#pragma unroll
    for (int kk = 0; kk < 2; ++kk) {
      bf16x8 af[2], bfr[2];
#pragma unroll
      for (int mi = 0; mi < 2; ++mi) {
        int r = mb + mi * 16 + lh;
        af[mi] = *(const bf16x8*)(As + r * 64 + (((kk * 4 + lg) ^ (r & 7)) << 3));
      }
#pragma unroll
      for (int ni = 0; ni < 2; ++ni) {
        int r = nb + ni * 16 + lh;
        bfr[ni] = *(const bf16x8*)(Bs + r * 64 + (((kk * 4 + lg) ^ (r & 7)) << 3));
      }
#pragma unroll
      for (int mi = 0; mi < 2; ++mi)
#pragma unroll
        for (int ni = 0; ni < 2; ++ni)
          acc[mi][ni] = mfma16(af[mi], bfr[ni], acc[mi][ni]);
    }
  }
#pragma unroll
  for (int mi = 0; mi < 2; ++mi)
#pragma unroll
    for (int ni = 0; ni < 2; ++ni)
#pragma unroll
      for (int i = 0; i < 4; ++i) {
        int row = m0 + mb + mi * 16 + lg * 4 + i;  // C/D: col=lane&15, row=(lane>>4)*4+reg
        int col = n0 + nb + ni * 16 + lh;
        float v = acc[mi][ni][i] + bias[col];
        if (EPI == 0) outf[(size_t)row * N + col] = v;
        else outb[(size_t)row * N + col] = (bf16)fmaxf(v, 0.f);
      }
}

// ---------------- QKV projection (N=64 per head per matrix) ----------------
__global__ __launch_bounds__(256) void qkv_gemm(
    const bf16* __restrict__ xb, const bf16* __restrict__ wT,
    const float* __restrict__ bq, const float* __restrict__ bk,
    const float* __restrict__ bv,
    bf16* __restrict__ qo, bf16* __restrict__ ko, bf16* __restrict__ vo) {
  __shared__ bf16 As[64 * 64];
  __shared__ bf16 Bs[64 * 64];
  const int tid = threadIdx.x;
  const int w = tid >> 6, l = tid & 63;
  const int lh = l & 15, lg = l >> 4;
  const int m0 = blockIdx.x * 64;
  const int idx = blockIdx.y;  // mat*8 + h
  const int mat = idx >> 3, h = idx & 7;
  const bf16* Bt = wT + (size_t)idx * 64 * 512;
  const float* bias = (mat == 0 ? bq : mat == 1 ? bk : bv) + h * 64;
  bf16* out = (mat == 0 ? qo : mat == 1 ? ko : vo);
  const float scale = (mat == 0) ? 0.125f : 1.0f;  // fold 1/sqrt(64) into Q
  const int mb = (w & 1) * 32, nb = (w >> 1) * 32;
  f32x4 acc[2][2] = {};
  for (int kt = 0; kt < 512; kt += 64) {
    __syncthreads();
#pragma unroll
    for (int p = 0; p < 2; ++p) {
      int c = p * 256 + tid;
      int r = c >> 3, cc = c & 7;
      int kk = kt + ((cc ^ (r & 7)) << 3);
      gll16(xb + (size_t)(m0 + r) * 512 + kk, As + c * 8);
      gll16(Bt + (size_t)r * 512 + kk, Bs + c * 8);
    }
    __syncthreads();
#pragma unroll
    for (int kk = 0; kk < 2; ++kk) {
      bf16x8 af[2], bfr[2];
#pragma unroll
      for (int mi = 0; mi < 2; ++mi) {
        int r = mb + mi * 16 + lh;
        af[mi] = *(const bf16x8*)(As + r * 64 + (((kk * 4 + lg) ^ (r & 7)) << 3));
      }
#pragma unroll
      for (int ni = 0; ni < 2; ++ni) {
        int r = nb + ni * 16 + lh;
        bfr[ni] = *(const bf16x8*)(Bs + r * 64 + (((kk * 4 + lg) ^ (r & 7)) << 3));
      }
#pragma unroll
      for (int mi = 0; mi < 2; ++mi)
#pragma unroll
        for (int ni = 0; ni < 2; ++ni)
          acc[mi][ni] = mfma16(af[mi], bfr[ni], acc[mi][ni]);
    }
  }
#pragma unroll
  for (int mi = 0; mi < 2; ++mi)
#pragma unroll
    for (int ni = 0; ni < 2; ++ni)
#pragma unroll
      for (int i = 0; i < 4; ++i) {
        int row = m0 + mb + mi * 16 + lg * 4 + i;
        int col = nb + ni * 16 + lh;
        int b = row >> 11, s = row & 2047;
        out[((size_t)(b * 8 + h) * 2048 + s) * 64 + col] =
            (bf16)((acc[mi][ni][i] + bias[col]) * scale);
      }
}

// ---------------- flash attention fwd (full, non-causal) ----------------
// grid (S/64, B*H); 4 waves, wave owns 16 q-rows. S^T = mfma(K, Q^T) so softmax
// reduce over keys = regs + shfl_xor(16/32). Q pre-scaled by 0.125.
__global__ __launch_bounds__(256) void attn_fwd(
    const bf16* __restrict__ Q, const bf16* __restrict__ Kg,
    const bf16* __restrict__ Vg, bf16* __restrict__ Y) {
  __shared__ bf16 Ks[32 * 64];      // swizzled [key][dh]
  __shared__ bf16 Vt[64 * 40];      // [dh][key] padded to 40
  __shared__ bf16 Pt[4][32 * 16];   // per-wave [key][q]
  const int tid = threadIdx.x;
  const int w = tid >> 6, l = tid & 63;
  const int lh = l & 15, lg = l >> 4;
  const int bh = blockIdx.y;
  const bf16* Qs = Q + (size_t)bh * 2048 * 64;
  const bf16* KsG = Kg + (size_t)bh * 2048 * 64;
  const bf16* VsG = Vg + (size_t)bh * 2048 * 64;
  const int q0 = blockIdx.x * 64 + w * 16;
  bf16x8 qf0 = *(const bf16x8*)(Qs + (size_t)(q0 + lh) * 64 + lg * 8);
  bf16x8 qf1 = *(const bf16x8*)(Qs + (size_t)(q0 + lh) * 64 + 32 + lg * 8);
  f32x4 oacc[4] = {};
  float m_run = -1e30f, l_run = 0.f;
  const int vkey = tid >> 3, vj = tid & 7;
  for (int k0 = 0; k0 < 2048; k0 += 32) {
    __syncthreads();
    {  // stage K tile (swizzled source, linear LDS)
      int r = tid >> 3, cc = tid & 7;
      gll16(KsG + (size_t)(k0 + r) * 64 + ((cc ^ (r & 7)) << 3), Ks + tid * 8);
    }
    {  // stage V transposed
      bf16x8 vv = *(const bf16x8*)(VsG + (size_t)(k0 + vkey) * 64 + vj * 8);
#pragma unroll
      for (int j = 0; j < 8; ++j) Vt[(vj * 8 + j) * 40 + vkey] = vv[j];
    }
    __syncthreads();
    // S^T tile: rows=keys, cols=q
    f32x4 st[2];
#pragma unroll
    for (int kg = 0; kg < 2; ++kg) {
      int r = kg * 16 + lh;
      bf16x8 kf0 = *(const bf16x8*)(Ks + r * 64 + ((lg ^ (r & 7)) << 3));
      bf16x8 kf1 = *(const bf16x8*)(Ks + r * 64 + (((4 + lg) ^ (r & 7)) << 3));
      f32x4 z = {};
      z = mfma16(kf0, qf0, z);
      z = mfma16(kf1, qf1, z);
      st[kg] = z;
    }
    // online softmax over 32 keys (per lane: 8 regs; cross: xor 16, 32)
    float cmax = -1e30f;
#pragma unroll
    for (int kg = 0; kg < 2; ++kg)
#pragma unroll
      for (int i = 0; i < 4; ++i) cmax = fmaxf(cmax, st[kg][i]);
    cmax = fmaxf(cmax, __shfl_xor(cmax, 16, 64));
    cmax = fmaxf(cmax, __shfl_xor(cmax, 32, 64));
    float m_new = fmaxf(m_run, cmax);
    float scl = __expf(m_run - m_new);
    float psum = 0.f;
    float pv[2][4];
#pragma unroll
    for (int kg = 0; kg < 2; ++kg)
#pragma unroll
      for (int i = 0; i < 4; ++i) {
        pv[kg][i] = __expf(st[kg][i] - m_new);
        psum += pv[kg][i];
      }
    psum += __shfl_xor(psum, 16, 64);
    psum += __shfl_xor(psum, 32, 64);
    l_run = l_run * scl + psum;
    m_run = m_new;
#pragma unroll
    for (int kg = 0; kg < 2; ++kg)
#pragma unroll
      for (int i = 0; i < 4; ++i)
        Pt[w][(kg * 16 + lg * 4 + i) * 16 + lh] = (bf16)pv[kg][i];
    asm volatile("s_waitcnt lgkmcnt(0)" ::: "memory");  // same-wave Pt write->read
#pragma unroll
    for (int f = 0; f < 4; ++f)
#pragma unroll
      for (int i = 0; i < 4; ++i) oacc[f][i] *= scl;
    bf16x8 pb;
#pragma unroll
    for (int i = 0; i < 8; ++i) pb[i] = Pt[w][(lg * 8 + i) * 16 + lh];
#pragma unroll
    for (int f = 0; f < 4; ++f) {
      bf16x8 va = *(const bf16x8*)(Vt + (f * 16 + lh) * 40 + lg * 8);
      oacc[f] = mfma16(va, pb, oacc[f]);  // Y^T frag: rows=dh, cols=q
    }
  }
  const float inv = 1.f / l_run;
  const int b = bh >> 3, h = bh & 7;
#pragma unroll
  for (int f = 0; f < 4; ++f)
#pragma unroll
    for (int i = 0; i < 4; ++i) {
      int dh = f * 16 + lg * 4 + i;
      int qq = q0 + lh;
      Y[((size_t)(b * 2048 + qq)) * 512 + h * 64 + dh] = (bf16)(oacc[f][i] * inv);
    }
}

// ---------------- fused residual add + LayerNorm (row = 512) ----------------
__global__ __launch_bounds__(256) void add_ln_k(
    const float* __restrict__ A, const float* __restrict__ Bv,
    const float* __restrict__ gamma, const float* __restrict__ beta,
    float* __restrict__ outf, bf16* __restrict__ outb) {
  const int row = blockIdx.x, tid = threadIdx.x;
  const float2 a = ((const float2*)(A + (size_t)row * 512))[tid];
  const float2 b = ((const float2*)(Bv + (size_t)row * 512))[tid];
  float s0 = a.x + b.x, s1 = a.y + b.y;
  float sum = s0 + s1;
#pragma unroll
  for (int m = 1; m < 64; m <<= 1) sum += __shfl_xor(sum, m, 64);
  __shared__ float part[4], part2[4];
  const int w = tid >> 6, l = tid & 63;
  if (l == 0) part[w] = sum;
  __syncthreads();
  const float mean = (part[0] + part[1] + part[2] + part[3]) * (1.f / 512.f);
  const float d0 = s0 - mean, d1 = s1 - mean;
  float vs = d0 * d0 + d1 * d1;
#pragma unroll
  for (int m = 1; m < 64; m <<= 1) vs += __shfl_xor(vs, m, 64);
  if (l == 0) part2[w] = vs;
  __syncthreads();
  const float var = (part2[0] + part2[1] + part2[2] + part2[3]) * (1.f / 512.f);
  const float inv = rsqrtf(var);  // reference has no epsilon
  const int c = tid * 2;
  const float o0 = gamma[c] * (d0 * inv) + beta[c];
  const float o1 = gamma[c + 1] * (d1 * inv) + beta[c + 1];
  ((float2*)(outf + (size_t)row * 512))[tid] = make_float2(o0, o1);
  if (outb) {
    outb[(size_t)row * 512 + c] = (bf16)o0;
    outb[(size_t)row * 512 + c + 1] = (bf16)o1;
  }
}

// ---------------- launch ----------------
extern "C" void kernel_launch(void* const* d_in, const int* in_sizes, int n_in,
                              void* d_out, int out_size, void* d_ws, size_t ws_size,
                              hipStream_t stream) {
  const float* x = (const float*)d_in[0];
  const float* wq = (const float*)d_in[1];
  const float* bq = (const float*)d_in[2];
  const float* wk = (const float*)d_in[3];
  const float* bk = (const float*)d_in[4];
  const float* wv = (const float*)d_in[5];
  const float* bv = (const float*)d_in[6];
  const float* wo = (const float*)d_in[7];
  const float* bo = (const float*)d_in[8];
  const float* g1 = (const float*)d_in[9];
  const float* be1 = (const float*)d_in[10];
  const float* w1 = (const float*)d_in[11];
  const float* b1 = (const float*)d_in[12];
  const float* w2 = (const float*)d_in[13];
  const float* b2 = (const float*)d_in[14];
  const float* g2 = (const float*)d_in[15];
  const float* be2 = (const float*)d_in[16];

  char* ws = (char*)d_ws;
  bf16* xb    = (bf16*)(ws + 0);         // 4 MiB
  bf16* wqkvT = (bf16*)(ws + 4194304);   // 1.5 MiB  [mat][h][64][512]
  bf16* woT   = (bf16*)(ws + 5767168);   // 0.5 MiB  [512][512]
  bf16* w1T   = (bf16*)(ws + 6291456);   // 2 MiB    [2048][512]
  bf16* w2T   = (bf16*)(ws + 8388608);   // 2 MiB    [512][2048]
  bf16* qb    = (bf16*)(ws + 10485760);  // 4 MiB    [B][H][S][DH]
  bf16* kb    = (bf16*)(ws + 14680064);  // 4 MiB
  bf16* vb    = (bf16*)(ws + 18874368);  // 4 MiB
  bf16* yb    = (bf16*)(ws + 23068672);  // 4 MiB    [B*S][512]
  float* t0   = (float*)(ws + 27262976); // 8 MiB
  float* y1   = (float*)(ws + 35651584); // 8 MiB
  bf16* y1b   = (bf16*)(ws + 44040192);  // 4 MiB
  bf16* f1    = (bf16*)(ws + 10485760);  // 16 MiB, aliases qb..yb (dead by then)
  float* f2   = t0;                      // aliases t0 (dead by then)

  cast_bf16_k<<<1024, 256, 0, stream>>>(x, xb, 4096 * 512);
  transpose_cast_k<<<512, 256, 0, stream>>>(wq, wqkvT, 8, 512, 64);
  transpose_cast_k<<<512, 256, 0, stream>>>(wk, wqkvT + 262144, 8, 512, 64);
  transpose_cast_k<<<512, 256, 0, stream>>>(wv, wqkvT + 524288, 8, 512, 64);
  transpose_cast_k<<<512, 256, 0, stream>>>(wo, woT, 1, 512, 512);
  transpose_cast_k<<<1024, 256, 0, stream>>>(w1, w1T, 1, 512, 2048);
  transpose_cast_k<<<1024, 256, 0, stream>>>(w2, w2T, 1, 2048, 512);

  qkv_gemm<<<dim3(64, 24), 256, 0, stream>>>(xb, wqkvT, bq, bk, bv, qb, kb, vb);
  attn_fwd<<<dim3(32, 16), 256, 0, stream>>>(qb, kb, vb, yb);
  gemm64<0><<<dim3(64, 8), 256, 0, stream>>>(yb, woT, bo, t0, nullptr, 4096, 512, 512);
  add_ln_k<<<4096, 256, 0, stream>>>(t0, x, g1, be1, y1, y1b);
  gemm64<1><<<dim3(64, 32), 256, 0, stream>>>(y1b, w1T, b1, nullptr, f1, 4096, 2048, 512);
  gemm64<0><<<dim3(64, 8), 256, 0, stream>>>(f1, w2T, b2, f2, nullptr, 4096, 512, 2048);
  add_ln_k<<<4096, 256, 0, stream>>>(f2, y1, g2, be2, (float*)d_out, nullptr);
}

// Round 3
// 165.797 us; speedup vs baseline: 1.1861x; 1.1861x over previous
//
#include <hip/hip_runtime.h>

typedef __bf16 bf16;
typedef __attribute__((ext_vector_type(8))) __bf16 bf16x8;
typedef __attribute__((ext_vector_type(4))) float f32x4;
typedef __attribute__((ext_vector_type(16))) float f32x16;

#define DEV __device__ __forceinline__

DEV f32x4 mfma16(bf16x8 a, bf16x8 b, f32x4 c) {
  return __builtin_amdgcn_mfma_f32_16x16x32_bf16(a, b, c, 0, 0, 0);
}
DEV f32x16 mfma32(bf16x8 a, bf16x8 b, f32x16 c) {
  return __builtin_amdgcn_mfma_f32_32x32x16_bf16(a, b, c, 0, 0, 0);
}
// async global->LDS, 16B/lane; LDS dest must be wave-linear (base + lane*16)
DEV void gll16(const bf16* g, bf16* l) {
  __builtin_amdgcn_global_load_lds(
      (const __attribute__((address_space(1))) void*)g,
      (__attribute__((address_space(3))) void*)l, 16, 0, 0);
}
DEV unsigned cvtpk(float a, float b) {
  unsigned r;
  asm("v_cvt_pk_bf16_f32 %0, %1, %2" : "=v"(r) : "v"(a), "v"(b));
  return r;
}
// v_permlane32_swap_b32 vdst, vsrc : vdst.hi(lanes>=32) <-> vsrc.lo(lanes<32)
DEV void pl32swap(unsigned& x, unsigned& y) {
  asm("v_permlane32_swap_b32 %0, %1" : "+v"(x), "+v"(y));
}

// ---------------- prep kernels ----------------
__global__ void cast_bf16_k(const float* __restrict__ in, bf16* __restrict__ out, int n8) {
  int i = blockIdx.x * blockDim.x + threadIdx.x;
  if (i >= n8) return;
  const float4* p = (const float4*)in + (size_t)i * 2;
  float4 a = p[0], b = p[1];
  bf16x8 o;
  o[0] = (bf16)a.x; o[1] = (bf16)a.y; o[2] = (bf16)a.z; o[3] = (bf16)a.w;
  o[4] = (bf16)b.x; o[5] = (bf16)b.y; o[6] = (bf16)b.z; o[7] = (bf16)b.w;
  ((bf16x8*)out)[i] = o;
}

// in fp32 [Bn][R][C] -> out bf16 [Bn][C][R]
__global__ void transpose_cast_k(const float* __restrict__ in, bf16* __restrict__ out,
                                 int Bn, int R, int C) {
  int total = Bn * R * C;
  for (int i = blockIdx.x * blockDim.x + threadIdx.x; i < total; i += gridDim.x * blockDim.x) {
    int b = i / (R * C);
    int rem = i - b * R * C;
    int r = rem / C, c = rem - r * C;
    out[(size_t)b * R * C + (size_t)c * R + r] = (bf16)in[i];
  }
}

__global__ void build_cb_k(const float* __restrict__ bq, const float* __restrict__ bk,
                           const float* __restrict__ bv, float* __restrict__ cb) {
  int i = blockIdx.x * blockDim.x + threadIdx.x;
  if (i < 1536) cb[i] = i < 512 ? bq[i] : (i < 1024 ? bk[i - 512] : bv[i - 1024]);
}

// V^T extract: qkv [4096][1536] (V at col 1024+h*64) -> vtb [bh][64 dh][2048 s]
__global__ __launch_bounds__(256) void vtrans_k(const bf16* __restrict__ qkv,
                                                bf16* __restrict__ vtb) {
  __shared__ bf16 tile[64 * 68];
  const int tid = threadIdx.x;
  const int s0 = blockIdx.x * 64;
  const int bh = blockIdx.y, b = bh >> 3, hh = bh & 7;
  const bf16* src = qkv + 1024 + hh * 64;
#pragma unroll
  for (int j = 0; j < 2; ++j) {
    int slot = j * 256 + tid;
    int r = slot >> 3, cc = slot & 7;
    *(bf16x8*)(tile + r * 68 + cc * 8) =
        *(const bf16x8*)(src + (size_t)(b * 2048 + s0 + r) * 1536 + cc * 8);
  }
  __syncthreads();
  const int w = tid >> 6, lane = tid & 63;
#pragma unroll
  for (int sb2 = 0; sb2 < 2; ++sb2) {
    int sb = w * 2 + sb2;
    bf16x8 v;
#pragma unroll
    for (int jj = 0; jj < 8; ++jj) v[jj] = tile[(sb * 8 + jj) * 68 + lane];
    *(bf16x8*)(vtb + (size_t)bh * 131072 + (size_t)lane * 2048 + s0 + sb * 8) = v;
  }
}

// ---------------- 128x128 tile GEMM (m97 structure) ----------------
// C[M][N] = A[M][K] * Bt[N][K]^T + bias
// EPI 0: f32 out; EPI 1: bf16 relu out; EPI 2: bf16 out, cols<512 scaled by 1/8 (QKV)
template <int EPI>
__global__ __launch_bounds__(256) void gemm128(
    const bf16* __restrict__ A, const bf16* __restrict__ Bt,
    const float* __restrict__ bias, float* __restrict__ outf,
    bf16* __restrict__ outb, int M, int N, int K) {
  __shared__ bf16 As[128 * 64];
  __shared__ bf16 Bs[128 * 64];
  const int tid = threadIdx.x;
  const int w = tid >> 6, l = tid & 63;
  const int lh = l & 15, lg = l >> 4;
  const int m0 = blockIdx.x * 128, n0 = blockIdx.y * 128;
  const int mb = (w & 1) * 64, nb = (w >> 1) * 64;
  f32x4 acc[4][4] = {};
  for (int kt = 0; kt < K; kt += 64) {
    __syncthreads();
#pragma unroll
    for (int j = 0; j < 4; ++j) {
      int slot = j * 256 + tid;
      int r = slot >> 3, cc = slot & 7;
      int kk = kt + ((cc ^ (r & 7)) << 3);  // swizzle SOURCE, LDS stays linear
      gll16(A + (size_t)(m0 + r) * K + kk, As + slot * 8);
      gll16(Bt + (size_t)(n0 + r) * K + kk, Bs + slot * 8);
    }
    __syncthreads();
#pragma unroll
    for (int kk = 0; kk < 2; ++kk) {
      bf16x8 af[4], bfr[4];
#pragma unroll
      for (int mi = 0; mi < 4; ++mi) {
        int r = mb + mi * 16 + lh;
        af[mi] = *(const bf16x8*)(As + r * 64 + (((kk * 4 + lg) ^ (r & 7)) << 3));
      }
#pragma unroll
      for (int ni = 0; ni < 4; ++ni) {
        int r = nb + ni * 16 + lh;
        bfr[ni] = *(const bf16x8*)(Bs + r * 64 + (((kk * 4 + lg) ^ (r & 7)) << 3));
      }
#pragma unroll
      for (int mi = 0; mi < 4; ++mi)
#pragma unroll
        for (int ni = 0; ni < 4; ++ni)
          acc[mi][ni] = mfma16(af[mi], bfr[ni], acc[mi][ni]);
    }
  }
#pragma unroll
  for (int mi = 0; mi < 4; ++mi)
#pragma unroll
    for (int ni = 0; ni < 4; ++ni)
#pragma unroll
      for (int i = 0; i < 4; ++i) {
        int row = m0 + mb + mi * 16 + lg * 4 + i;  // C/D: col=lane&15, row=(lane>>4)*4+reg
        int col = n0 + nb + ni * 16 + lh;
        float v = acc[mi][ni][i] + bias[col];
        if (EPI == 0) outf[(size_t)row * N + col] = v;
        else if (EPI == 1) outb[(size_t)row * N + col] = (bf16)fmaxf(v, 0.f);
        else outb[(size_t)row * N + col] = (bf16)(col < 512 ? v * 0.125f : v);
      }
}

// ---------------- flash attention fwd ----------------
// grid (16 qtiles, 16 bh); 8 waves. Waves 0-3: keys [0,1024), waves 4-7: [1024,2048),
// pair (w, w+4) shares q-rows qtile*128 + (w&3)*32 .. +32. 32x32x16 MFMA,
// swapped QK^T (S^T = K·Q^T), in-register softmax, P via cvt_pk+permlane32_swap.
__global__ __launch_bounds__(512) void attn_fwd2(
    const bf16* __restrict__ qkv,  // [4096][1536], Q pre-scaled by 1/8
    const bf16* __restrict__ vtb,  // [bh][64][2048]
    bf16* __restrict__ Y) {        // [4096][512]
  __shared__ __align__(16) char lds[65536];
  const int tid = threadIdx.x;
  const int w = tid >> 6, lane = tid & 63;
  const int l31 = lane & 31, h = lane >> 5;
  const int bh = blockIdx.y, b = bh >> 3, hh = bh & 7;
  const int qtile = blockIdx.x;
  const int half = w >> 2, wp = w & 3;
  const int q0 = qtile * 128 + wp * 32;
  const int tl = tid & 255, sh = tid >> 8;

  // Q B-frags: qf[g] = Q[q0+l31][g*16 + h*8 .. +8]
  bf16x8 qf[4];
  {
    const size_t rowQ = (size_t)(b * 2048 + q0 + l31) * 1536 + hh * 64;
#pragma unroll
    for (int g = 0; g < 4; ++g)
      qf[g] = *(const bf16x8*)(qkv + rowQ + g * 16 + h * 8);
  }
  const bf16* Kp = qkv + 512 + hh * 64;
  const bf16* Vp = vtb + (size_t)bh * 131072;

  f32x16 oacc[2] = {};
  float m_run = -1e30f, l_run = 0.f;

#define KBUF(d, hf) ((bf16*)(lds + (d) * 32768 + (hf) * 16384))
#define VBUF(d, hf) ((bf16*)(lds + (d) * 32768 + (hf) * 16384 + 8192))

  // stage iteration i into dbuf d (each half stages its own K,V^T 64x64 tiles)
  auto stage = [&](int i, int d) {
    const int k0 = sh * 1024 + i * 64;
#pragma unroll
    for (int j = 0; j < 2; ++j) {
      int slot = j * 256 + tl;
      int r = slot >> 3, cc = slot & 7;
      gll16(Kp + (size_t)(b * 2048 + k0 + r) * 1536 + ((cc ^ (r & 7)) << 3),
            KBUF(d, sh) + slot * 8);
      gll16(Vp + (size_t)r * 2048 + k0 + ((cc ^ (r & 7)) << 3),
            VBUF(d, sh) + slot * 8);
    }
  };

  stage(0, 0);
  __syncthreads();
  for (int i = 0; i < 16; ++i) {
    const int d = i & 1;
    if (i < 15) stage(i + 1, d ^ 1);
    const bf16* Kt = KBUF(d, half);
    const bf16* Vt = VBUF(d, half);
    // S^T tiles [32 keys x 32 q], keys kt*32 + (r&3)+8*(r>>2)+4h
    f32x16 st[2];
#pragma unroll
    for (int kt = 0; kt < 2; ++kt) {
      f32x16 z = {};
      const int r = kt * 32 + l31;
#pragma unroll
      for (int g = 0; g < 4; ++g) {
        bf16x8 kf = *(const bf16x8*)(Kt + r * 64 + (((2 * g + h) ^ (r & 7)) << 3));
        z = mfma32(kf, qf[g], z);
      }
      st[kt] = z;
    }
    // online softmax over 64 keys (32 regs/lane + cross-half)
    float mx = -1e30f;
#pragma unroll
    for (int kt = 0; kt < 2; ++kt)
#pragma unroll
      for (int r = 0; r < 16; ++r) mx = fmaxf(mx, st[kt][r]);
    mx = fmaxf(mx, __shfl_xor(mx, 32, 64));
    const float m_new = fmaxf(m_run, mx);
    const float scl = __expf(m_run - m_new);
    m_run = m_new;
    float ps = 0.f;
#pragma unroll
    for (int kt = 0; kt < 2; ++kt)
#pragma unroll
      for (int r = 0; r < 16; ++r) {
        float e = __expf(st[kt][r] - m_new);
        st[kt][r] = e;
        ps += e;
      }
    ps += __shfl_xor(ps, 32, 64);
    l_run = l_run * scl + ps;
    oacc[0] = oacc[0] * scl;
    oacc[1] = oacc[1] * scl;
    // pack P^T B-frags: per 16-key group, dwords {a0,a1,b0,b1}
    // pl32swap(a,b): a.hi <-> b.lo  =>  a: h0 keeps (0,1), h1 gets (8,9);
    //                                   b: h0 gets (4,5), h1 keeps (12,13).
    bf16x8 pf[4];
#pragma unroll
    for (int kt = 0; kt < 2; ++kt)
#pragma unroll
      for (int g = 0; g < 2; ++g) {
        unsigned a0 = cvtpk(st[kt][8 * g + 0], st[kt][8 * g + 1]);
        unsigned a1 = cvtpk(st[kt][8 * g + 2], st[kt][8 * g + 3]);
        unsigned b0 = cvtpk(st[kt][8 * g + 4], st[kt][8 * g + 5]);
        unsigned b1 = cvtpk(st[kt][8 * g + 6], st[kt][8 * g + 7]);
        pl32swap(a0, b0);
        pl32swap(a1, b1);
        union { unsigned u[4]; bf16x8 v; } pk;
        pk.u[0] = a0; pk.u[1] = a1; pk.u[2] = b0; pk.u[3] = b1;
        pf[kt * 2 + g] = pk.v;
      }
    // PV: Y^T[dh][q] += V^T frag x P frag
#pragma unroll
    for (int t = 0; t < 2; ++t) {
      const int r = t * 32 + l31;
#pragma unroll
      for (int kg = 0; kg < 4; ++kg) {
        bf16x8 vf = *(const bf16x8*)(Vt + r * 64 + (((2 * kg + h) ^ (r & 7)) << 3));
        oacc[t] = mfma32(vf, pf[kg], oacc[t]);
      }
    }
    __syncthreads();
  }

  // ---- merge split-KV halves ----
  // lds reuse: Ost [pair p][8 chunks][64 lanes][16B] @0 (32KB); m,l @32768 (2KB); Ytile @34816
  if (half == 1) {
    char* ob = lds + wp * 8192;
#pragma unroll
    for (int t = 0; t < 2; ++t)
#pragma unroll
      for (int c = 0; c < 4; ++c) {
        f32x4 v4 = {oacc[t][c * 4 + 0], oacc[t][c * 4 + 1],
                    oacc[t][c * 4 + 2], oacc[t][c * 4 + 3]};
        *(f32x4*)(ob + (t * 4 + c) * 1024 + lane * 16) = v4;
      }
    ((float2*)(lds + 32768))[wp * 64 + lane] = make_float2(m_run, l_run);
  }
  __syncthreads();
  bf16* Yt = (bf16*)(lds + 34816);  // [128 q][72 dh]
  if (half == 0) {
    float2 ml2 = ((const float2*)(lds + 32768))[wp * 64 + lane];
    const float mstar = fmaxf(m_run, ml2.x);
    const float e1 = __expf(m_run - mstar), e2 = __expf(ml2.x - mstar);
    const float lstar = l_run * e1 + ml2.y * e2;
    const float r1 = e1 / lstar, r2 = e2 / lstar;
    const char* ob = lds + wp * 8192;
#pragma unroll
    for (int t = 0; t < 2; ++t)
#pragma unroll
      for (int c = 0; c < 4; ++c) {
        f32x4 v4 = *(const f32x4*)(ob + (t * 4 + c) * 1024 + lane * 16);
#pragma unroll
        for (int j = 0; j < 4; ++j)
          oacc[t][c * 4 + j] = oacc[t][c * 4 + j] * r1 + v4[j] * r2;
      }
#pragma unroll
    for (int t = 0; t < 2; ++t)
#pragma unroll
      for (int r = 0; r < 16; ++r) {
        int dh = (r & 3) + 8 * (r >> 2) + 4 * h + 32 * t;
        Yt[(wp * 32 + l31) * 72 + dh] = (bf16)oacc[t][r];
      }
  }
  __syncthreads();
#pragma unroll
  for (int it = 0; it < 2; ++it) {
    int s = it * 512 + tid;
    int ql = s >> 3, cbk = s & 7;
    bf16x8 v = *(const bf16x8*)(Yt + ql * 72 + cbk * 8);
    *(bf16x8*)(Y + (size_t)(b * 2048 + qtile * 128 + ql) * 512 + hh * 64 + cbk * 8) = v;
  }
#undef KBUF
#undef VBUF
}

// ---------------- fused residual add + LayerNorm (row = 512) ----------------
__global__ __launch_bounds__(256) void add_ln_k(
    const float* __restrict__ A, const float* __restrict__ Bv,
    const float* __restrict__ gamma, const float* __restrict__ beta,
    float* __restrict__ outf, bf16* __restrict__ outb) {
  const int row = blockIdx.x, tid = threadIdx.x;
  const float2 a = ((const float2*)(A + (size_t)row * 512))[tid];
  const float2 b = ((const float2*)(Bv + (size_t)row * 512))[tid];
  float s0 = a.x + b.x, s1 = a.y + b.y;
  float sum = s0 + s1;
#pragma unroll
  for (int m = 1; m < 64; m <<= 1) sum += __shfl_xor(sum, m, 64);
  __shared__ float part[4], part2[4];
  const int w = tid >> 6, l = tid & 63;
  if (l == 0) part[w] = sum;
  __syncthreads();
  const float mean = (part[0] + part[1] + part[2] + part[3]) * (1.f / 512.f);
  const float d0 = s0 - mean, d1 = s1 - mean;
  float vs = d0 * d0 + d1 * d1;
#pragma unroll
  for (int m = 1; m < 64; m <<= 1) vs += __shfl_xor(vs, m, 64);
  if (l == 0) part2[w] = vs;
  __syncthreads();
  const float var = (part2[0] + part2[1] + part2[2] + part2[3]) * (1.f / 512.f);
  const float inv = rsqrtf(var);
  const int c = tid * 2;
  const float o0 = gamma[c] * (d0 * inv) + beta[c];
  const float o1 = gamma[c + 1] * (d1 * inv) + beta[c + 1];
  ((float2*)(outf + (size_t)row * 512))[tid] = make_float2(o0, o1);
  if (outb) {
    outb[(size_t)row * 512 + c] = (bf16)o0;
    outb[(size_t)row * 512 + c + 1] = (bf16)o1;
  }
}

// ---------------- launch ----------------
extern "C" void kernel_launch(void* const* d_in, const int* in_sizes, int n_in,
                              void* d_out, int out_size, void* d_ws, size_t ws_size,
                              hipStream_t stream) {
  const float* x = (const float*)d_in[0];
  const float* wq = (const float*)d_in[1];
  const float* bq = (const float*)d_in[2];
  const float* wk = (const float*)d_in[3];
  const float* bk = (const float*)d_in[4];
  const float* wv = (const float*)d_in[5];
  const float* bv = (const float*)d_in[6];
  const float* wo = (const float*)d_in[7];
  const float* bo = (const float*)d_in[8];
  const float* g1 = (const float*)d_in[9];
  const float* be1 = (const float*)d_in[10];
  const float* w1 = (const float*)d_in[11];
  const float* b1 = (const float*)d_in[12];
  const float* w2 = (const float*)d_in[13];
  const float* b2 = (const float*)d_in[14];
  const float* g2 = (const float*)d_in[15];
  const float* be2 = (const float*)d_in[16];

  char* ws = (char*)d_ws;
  // layout (aliasing by liveness):
  bf16* xb    = (bf16*)(ws + 0);          // 4MB, steps 1-5
  bf16* y1b   = (bf16*)(ws + 0);          // 4MB, steps 9-10 (aliases xb)
  bf16* wqkvT = (bf16*)(ws + 4194304);    // 1.5MB [1536][512]
  bf16* woT   = (bf16*)(ws + 5767168);    // 0.5MB
  bf16* w1T   = (bf16*)(ws + 6291456);    // 2MB
  bf16* w2T   = (bf16*)(ws + 8388608);    // 2MB
  float* cb   = (float*)(ws + 10485760);  // 8KB
  bf16* qkvb  = (bf16*)(ws + 10493952);   // 12MB [4096][1536], steps 5-7
  float* t0   = (float*)(ws + 10493952);  // 8MB, steps 8-9 (aliases qkvb)
  bf16* f1    = (bf16*)(ws + 10493952);   // 16MB [4096][2048], steps 10-11
  bf16* vtb   = (bf16*)(ws + 23078656);   // 4MB [16][64][2048], steps 6-7
  bf16* yb    = (bf16*)(ws + 27272960);   // 4MB [4096][512], steps 7-8
  float* f2   = (float*)(ws + 27272960);  // 8MB, steps 11-12 (aliases yb)
  float* y1   = (float*)(ws + 35661568);  // 8MB, steps 9-12

  cast_bf16_k<<<1024, 256, 0, stream>>>(x, xb, 262144);
  transpose_cast_k<<<512, 256, 0, stream>>>(wq, wqkvT, 8, 512, 64);
  transpose_cast_k<<<512, 256, 0, stream>>>(wk, wqkvT + 262144, 8, 512, 64);
  transpose_cast_k<<<512, 256, 0, stream>>>(wv, wqkvT + 524288, 8, 512, 64);
  transpose_cast_k<<<512, 256, 0, stream>>>(wo, woT, 1, 512, 512);
  transpose_cast_k<<<1024, 256, 0, stream>>>(w1, w1T, 1, 512, 2048);
  transpose_cast_k<<<1024, 256, 0, stream>>>(w2, w2T, 1, 2048, 512);
  build_cb_k<<<6, 256, 0, stream>>>(bq, bk, bv, cb);

  gemm128<2><<<dim3(32, 12), 256, 0, stream>>>(xb, wqkvT, cb, nullptr, qkvb, 4096, 1536, 512);
  vtrans_k<<<dim3(32, 16), 256, 0, stream>>>(qkvb, vtb);
  attn_fwd2<<<dim3(16, 16), 512, 0, stream>>>(qkvb, vtb, yb);
  gemm128<0><<<dim3(32, 4), 256, 0, stream>>>(yb, woT, bo, t0, nullptr, 4096, 512, 512);
  add_ln_k<<<4096, 256, 0, stream>>>(t0, x, g1, be1, y1, y1b);
  gemm128<1><<<dim3(32, 16), 256, 0, stream>>>(y1b, w1T, b1, nullptr, f1, 4096, 2048, 512);
  gemm128<0><<<dim3(32, 4), 256, 0, stream>>>(f1, w2T, b2, f2, nullptr, 4096, 512, 2048);
  add_ln_k<<<4096, 256, 0, stream>>>(f2, y1, g2, be2, (float*)d_out, nullptr);
}

// Round 4
// 142.764 us; speedup vs baseline: 1.3774x; 1.1613x over previous
//
#include <hip/hip_runtime.h>

typedef __bf16 bf16;
typedef __attribute__((ext_vector_type(8))) __bf16 bf16x8;
typedef __attribute__((ext_vector_type(4))) float f32x4;
typedef __attribute__((ext_vector_type(16))) float f32x16;

#define DEV __device__ __forceinline__

DEV f32x4 mfma16(bf16x8 a, bf16x8 b, f32x4 c) {
  return __builtin_amdgcn_mfma_f32_16x16x32_bf16(a, b, c, 0, 0, 0);
}
DEV f32x16 mfma32(bf16x8 a, bf16x8 b, f32x16 c) {
  return __builtin_amdgcn_mfma_f32_32x32x16_bf16(a, b, c, 0, 0, 0);
}
// async global->LDS, 16B/lane; LDS dest must be wave-linear (base + lane*16)
DEV void gll16(const bf16* g, bf16* l) {
  __builtin_amdgcn_global_load_lds(
      (const __attribute__((address_space(1))) void*)g,
      (__attribute__((address_space(3))) void*)l, 16, 0, 0);
}
DEV unsigned cvtpk(float a, float b) {
  unsigned r;
  asm("v_cvt_pk_bf16_f32 %0, %1, %2" : "=v"(r) : "v"(a), "v"(b));
  return r;
}
// v_permlane32_swap_b32 vdst, vsrc : vdst.hi(lanes>=32) <-> vsrc.lo(lanes<32)
DEV void pl32swap(unsigned& x, unsigned& y) {
  asm("v_permlane32_swap_b32 %0, %1" : "+v"(x), "+v"(y));
}

// ---------------- prep kernels ----------------
__global__ void cast_bf16_k(const float* __restrict__ in, bf16* __restrict__ out, int n8) {
  int i = blockIdx.x * blockDim.x + threadIdx.x;
  if (i >= n8) return;
  const float4* p = (const float4*)in + (size_t)i * 2;
  float4 a = p[0], b = p[1];
  bf16x8 o;
  o[0] = (bf16)a.x; o[1] = (bf16)a.y; o[2] = (bf16)a.z; o[3] = (bf16)a.w;
  o[4] = (bf16)b.x; o[5] = (bf16)b.y; o[6] = (bf16)b.z; o[7] = (bf16)b.w;
  ((bf16x8*)out)[i] = o;
}

// in fp32 [Bn][R][C] -> out bf16 [Bn][C][R]
__global__ void transpose_cast_k(const float* __restrict__ in, bf16* __restrict__ out,
                                 int Bn, int R, int C) {
  int total = Bn * R * C;
  for (int i = blockIdx.x * blockDim.x + threadIdx.x; i < total; i += gridDim.x * blockDim.x) {
    int b = i / (R * C);
    int rem = i - b * R * C;
    int r = rem / C, c = rem - r * C;
    out[(size_t)b * R * C + (size_t)c * R + r] = (bf16)in[i];
  }
}

__global__ void build_cb_k(const float* __restrict__ bq, const float* __restrict__ bk,
                           const float* __restrict__ bv, float* __restrict__ cb) {
  int i = blockIdx.x * blockDim.x + threadIdx.x;
  if (i < 1536) cb[i] = i < 512 ? bq[i] : (i < 1024 ? bk[i - 512] : bv[i - 1024]);
}

// V^T extract: qkv [4096][1536] (V at col 1024+h*64) -> vtb [bh][64 dh][2048 s]
__global__ __launch_bounds__(256) void vtrans_k(const bf16* __restrict__ qkv,
                                                bf16* __restrict__ vtb) {
  __shared__ bf16 tile[64 * 68];
  const int tid = threadIdx.x;
  const int s0 = blockIdx.x * 64;
  const int bh = blockIdx.y, b = bh >> 3, hh = bh & 7;
  const bf16* src = qkv + 1024 + hh * 64;
#pragma unroll
  for (int j = 0; j < 2; ++j) {
    int slot = j * 256 + tid;
    int r = slot >> 3, cc = slot & 7;
    *(bf16x8*)(tile + r * 68 + cc * 8) =
        *(const bf16x8*)(src + (size_t)(b * 2048 + s0 + r) * 1536 + cc * 8);
  }
  __syncthreads();
  const int w = tid >> 6, lane = tid & 63;
#pragma unroll
  for (int sb2 = 0; sb2 < 2; ++sb2) {
    int sb = w * 2 + sb2;
    bf16x8 v;
#pragma unroll
    for (int jj = 0; jj < 8; ++jj) v[jj] = tile[(sb * 8 + jj) * 68 + lane];
    *(bf16x8*)(vtb + (size_t)bh * 131072 + (size_t)lane * 2048 + s0 + sb * 8) = v;
  }
}

// ---------------- 128x64 tile GEMM, optional split-K ----------------
// C[M][N] = A[M][K] * Bt[N][K]^T ; grid (M/128, N/64, nsplit), klen = K/nsplit
// EPI 0: f32 partial out (NO bias), slice z at outf + z*M*N
// EPI 1: bf16 relu(acc+bias)
// EPI 2: bf16 acc+bias, cols<512 scaled by 1/8 (QKV fused Q-scale)
template <int EPI>
__global__ __launch_bounds__(256) void gemmN64(
    const bf16* __restrict__ A, const bf16* __restrict__ Bt,
    const float* __restrict__ bias, float* __restrict__ outf,
    bf16* __restrict__ outb, int M, int N, int K, int klen) {
  __shared__ bf16 As[128 * 64];
  __shared__ bf16 Bs[64 * 64];
  const int tid = threadIdx.x;
  const int w = tid >> 6, l = tid & 63;
  const int lh = l & 15, lg = l >> 4;
  const int m0 = blockIdx.x * 128, n0 = blockIdx.y * 64;
  const int k0 = blockIdx.z * klen;
  const int mb = (w & 1) * 64, nb = (w >> 1) * 32;
  f32x4 acc[4][2] = {};
  for (int kt = k0; kt < k0 + klen; kt += 64) {
    __syncthreads();
#pragma unroll
    for (int j = 0; j < 4; ++j) {
      int slot = j * 256 + tid;
      int r = slot >> 3, cc = slot & 7;
      int kk = kt + ((cc ^ (r & 7)) << 3);  // swizzle SOURCE, LDS stays linear
      gll16(A + (size_t)(m0 + r) * K + kk, As + slot * 8);
    }
#pragma unroll
    for (int j = 0; j < 2; ++j) {
      int slot = j * 256 + tid;
      int r = slot >> 3, cc = slot & 7;
      int kk = kt + ((cc ^ (r & 7)) << 3);
      gll16(Bt + (size_t)(n0 + r) * K + kk, Bs + slot * 8);
    }
    __syncthreads();
#pragma unroll
    for (int kk = 0; kk < 2; ++kk) {
      bf16x8 af[4], bfr[2];
#pragma unroll
      for (int mi = 0; mi < 4; ++mi) {
        int r = mb + mi * 16 + lh;
        af[mi] = *(const bf16x8*)(As + r * 64 + (((kk * 4 + lg) ^ (r & 7)) << 3));
      }
#pragma unroll
      for (int ni = 0; ni < 2; ++ni) {
        int r = nb + ni * 16 + lh;
        bfr[ni] = *(const bf16x8*)(Bs + r * 64 + (((kk * 4 + lg) ^ (r & 7)) << 3));
      }
#pragma unroll
      for (int mi = 0; mi < 4; ++mi)
#pragma unroll
        for (int ni = 0; ni < 2; ++ni)
          acc[mi][ni] = mfma16(af[mi], bfr[ni], acc[mi][ni]);
    }
  }
  float* op = (EPI == 0) ? outf + (size_t)blockIdx.z * M * N : nullptr;
#pragma unroll
  for (int mi = 0; mi < 4; ++mi)
#pragma unroll
    for (int ni = 0; ni < 2; ++ni)
#pragma unroll
      for (int i = 0; i < 4; ++i) {
        int row = m0 + mb + mi * 16 + lg * 4 + i;  // C/D: col=lane&15, row=(lane>>4)*4+reg
        int col = n0 + nb + ni * 16 + lh;
        float v = acc[mi][ni][i];
        if (EPI == 0) {
          op[(size_t)row * N + col] = v;
        } else if (EPI == 1) {
          v += bias[col];
          outb[(size_t)row * N + col] = (bf16)fmaxf(v, 0.f);
        } else {
          v += bias[col];
          outb[(size_t)row * N + col] = (bf16)(col < 512 ? v * 0.125f : v);
        }
      }
}

// ---------------- flash attention fwd ----------------
// grid (16 qtiles, 16 bh); 8 waves. Waves 0-3: keys [0,1024), waves 4-7: [1024,2048),
// pair (w, w+4) shares q-rows qtile*128 + (w&3)*32 .. +32. 32x32x16 MFMA,
// swapped QK^T (S^T = K·Q^T), in-register softmax, P via cvt_pk+permlane32_swap.
__global__ __launch_bounds__(512) void attn_fwd2(
    const bf16* __restrict__ qkv,  // [4096][1536], Q pre-scaled by 1/8
    const bf16* __restrict__ vtb,  // [bh][64][2048]
    bf16* __restrict__ Y) {        // [4096][512]
  __shared__ __align__(16) char lds[65536];
  const int tid = threadIdx.x;
  const int w = tid >> 6, lane = tid & 63;
  const int l31 = lane & 31, h = lane >> 5;
  const int bh = blockIdx.y, b = bh >> 3, hh = bh & 7;
  const int qtile = blockIdx.x;
  const int half = w >> 2, wp = w & 3;
  const int q0 = qtile * 128 + wp * 32;
  const int tl = tid & 255, sh = tid >> 8;

  // Q B-frags: qf[g] = Q[q0+l31][g*16 + h*8 .. +8]
  bf16x8 qf[4];
  {
    const size_t rowQ = (size_t)(b * 2048 + q0 + l31) * 1536 + hh * 64;
#pragma unroll
    for (int g = 0; g < 4; ++g)
      qf[g] = *(const bf16x8*)(qkv + rowQ + g * 16 + h * 8);
  }
  const bf16* Kp = qkv + 512 + hh * 64;
  const bf16* Vp = vtb + (size_t)bh * 131072;

  f32x16 oacc[2] = {};
  float m_run = -1e30f, l_run = 0.f;

#define KBUF(d, hf) ((bf16*)(lds + (d) * 32768 + (hf) * 16384))
#define VBUF(d, hf) ((bf16*)(lds + (d) * 32768 + (hf) * 16384 + 8192))

  // stage iteration i into dbuf d (each half stages its own K,V^T 64x64 tiles)
  auto stage = [&](int i, int d) {
    const int k0 = sh * 1024 + i * 64;
#pragma unroll
    for (int j = 0; j < 2; ++j) {
      int slot = j * 256 + tl;
      int r = slot >> 3, cc = slot & 7;
      gll16(Kp + (size_t)(b * 2048 + k0 + r) * 1536 + ((cc ^ (r & 7)) << 3),
            KBUF(d, sh) + slot * 8);
      gll16(Vp + (size_t)r * 2048 + k0 + ((cc ^ (r & 7)) << 3),
            VBUF(d, sh) + slot * 8);
    }
  };

  stage(0, 0);
  __syncthreads();
  for (int i = 0; i < 16; ++i) {
    const int d = i & 1;
    if (i < 15) stage(i + 1, d ^ 1);
    const bf16* Kt = KBUF(d, half);
    const bf16* Vt = VBUF(d, half);
    // S^T tiles [32 keys x 32 q], keys kt*32 + (r&3)+8*(r>>2)+4h
    f32x16 st[2];
#pragma unroll
    for (int kt = 0; kt < 2; ++kt) {
      f32x16 z = {};
      const int r = kt * 32 + l31;
#pragma unroll
      for (int g = 0; g < 4; ++g) {
        bf16x8 kf = *(const bf16x8*)(Kt + r * 64 + (((2 * g + h) ^ (r & 7)) << 3));
        z = mfma32(kf, qf[g], z);
      }
      st[kt] = z;
    }
    // online softmax over 64 keys (32 regs/lane + cross-half)
    float mx = -1e30f;
#pragma unroll
    for (int kt = 0; kt < 2; ++kt)
#pragma unroll
      for (int r = 0; r < 16; ++r) mx = fmaxf(mx, st[kt][r]);
    mx = fmaxf(mx, __shfl_xor(mx, 32, 64));
    const float m_new = fmaxf(m_run, mx);
    const float scl = __expf(m_run - m_new);
    m_run = m_new;
    float ps = 0.f;
#pragma unroll
    for (int kt = 0; kt < 2; ++kt)
#pragma unroll
      for (int r = 0; r < 16; ++r) {
        float e = __expf(st[kt][r] - m_new);
        st[kt][r] = e;
        ps += e;
      }
    ps += __shfl_xor(ps, 32, 64);
    l_run = l_run * scl + ps;
    oacc[0] = oacc[0] * scl;
    oacc[1] = oacc[1] * scl;
    // pack P^T B-frags: per 16-key group, dwords {a0,a1,b0,b1}
    // pl32swap(a,b): a.hi <-> b.lo  =>  a: h0 keeps (0,1), h1 gets (8,9);
    //                                   b: h0 gets (4,5), h1 keeps (12,13).
    bf16x8 pf[4];
#pragma unroll
    for (int kt = 0; kt < 2; ++kt)
#pragma unroll
      for (int g = 0; g < 2; ++g) {
        unsigned a0 = cvtpk(st[kt][8 * g + 0], st[kt][8 * g + 1]);
        unsigned a1 = cvtpk(st[kt][8 * g + 2], st[kt][8 * g + 3]);
        unsigned b0 = cvtpk(st[kt][8 * g + 4], st[kt][8 * g + 5]);
        unsigned b1 = cvtpk(st[kt][8 * g + 6], st[kt][8 * g + 7]);
        pl32swap(a0, b0);
        pl32swap(a1, b1);
        union { unsigned u[4]; bf16x8 v; } pk;
        pk.u[0] = a0; pk.u[1] = a1; pk.u[2] = b0; pk.u[3] = b1;
        pf[kt * 2 + g] = pk.v;
      }
    // PV: Y^T[dh][q] += V^T frag x P frag
#pragma unroll
    for (int t = 0; t < 2; ++t) {
      const int r = t * 32 + l31;
#pragma unroll
      for (int kg = 0; kg < 4; ++kg) {
        bf16x8 vf = *(const bf16x8*)(Vt + r * 64 + (((2 * kg + h) ^ (r & 7)) << 3));
        oacc[t] = mfma32(vf, pf[kg], oacc[t]);
      }
    }
    __syncthreads();
  }

  // ---- merge split-KV halves ----
  // lds reuse: Ost [pair p][8 chunks][64 lanes][16B] @0 (32KB); m,l @32768 (2KB); Ytile @34816
  if (half == 1) {
    char* ob = lds + wp * 8192;
#pragma unroll
    for (int t = 0; t < 2; ++t)
#pragma unroll
      for (int c = 0; c < 4; ++c) {
        f32x4 v4 = {oacc[t][c * 4 + 0], oacc[t][c * 4 + 1],
                    oacc[t][c * 4 + 2], oacc[t][c * 4 + 3]};
        *(f32x4*)(ob + (t * 4 + c) * 1024 + lane * 16) = v4;
      }
    ((float2*)(lds + 32768))[wp * 64 + lane] = make_float2(m_run, l_run);
  }
  __syncthreads();
  bf16* Yt = (bf16*)(lds + 34816);  // [128 q][72 dh]
  if (half == 0) {
    float2 ml2 = ((const float2*)(lds + 32768))[wp * 64 + lane];
    const float mstar = fmaxf(m_run, ml2.x);
    const float e1 = __expf(m_run - mstar), e2 = __expf(ml2.x - mstar);
    const float lstar = l_run * e1 + ml2.y * e2;
    const float r1 = e1 / lstar, r2 = e2 / lstar;
    const char* ob = lds + wp * 8192;
#pragma unroll
    for (int t = 0; t < 2; ++t)
#pragma unroll
      for (int c = 0; c < 4; ++c) {
        f32x4 v4 = *(const f32x4*)(ob + (t * 4 + c) * 1024 + lane * 16);
#pragma unroll
        for (int j = 0; j < 4; ++j)
          oacc[t][c * 4 + j] = oacc[t][c * 4 + j] * r1 + v4[j] * r2;
      }
#pragma unroll
    for (int t = 0; t < 2; ++t)
#pragma unroll
      for (int r = 0; r < 16; ++r) {
        int dh = (r & 3) + 8 * (r >> 2) + 4 * h + 32 * t;
        Yt[(wp * 32 + l31) * 72 + dh] = (bf16)oacc[t][r];
      }
  }
  __syncthreads();
#pragma unroll
  for (int it = 0; it < 2; ++it) {
    int s = it * 512 + tid;
    int ql = s >> 3, cbk = s & 7;
    bf16x8 v = *(const bf16x8*)(Yt + ql * 72 + cbk * 8);
    *(bf16x8*)(Y + (size_t)(b * 2048 + qtile * 128 + ql) * 512 + hh * 64 + cbk * 8) = v;
  }
#undef KBUF
#undef VBUF
}

// ---------------- fused: sum 2 split-K partials + bias + f32 residual -> LN -> bf16 ----------------
__global__ __launch_bounds__(256) void add_ln1_k(
    const float* __restrict__ P,  // [2][4096][512]
    const float* __restrict__ xres, const float* __restrict__ bias,
    const float* __restrict__ gamma, const float* __restrict__ beta,
    bf16* __restrict__ outb) {
  const int row = blockIdx.x, tid = threadIdx.x;
  const size_t base = (size_t)row * 512;
  const float2 p0 = ((const float2*)(P + base))[tid];
  const float2 p1 = ((const float2*)(P + 2097152 + base))[tid];
  const float2 xr = ((const float2*)(xres + base))[tid];
  const int c = tid * 2;
  float s0 = p0.x + p1.x + bias[c] + xr.x;
  float s1 = p0.y + p1.y + bias[c + 1] + xr.y;
  float sum = s0 + s1;
#pragma unroll
  for (int m = 1; m < 64; m <<= 1) sum += __shfl_xor(sum, m, 64);
  __shared__ float part[4], part2[4];
  const int w = tid >> 6, l = tid & 63;
  if (l == 0) part[w] = sum;
  __syncthreads();
  const float mean = (part[0] + part[1] + part[2] + part[3]) * (1.f / 512.f);
  const float d0 = s0 - mean, d1 = s1 - mean;
  float vs = d0 * d0 + d1 * d1;
#pragma unroll
  for (int m = 1; m < 64; m <<= 1) vs += __shfl_xor(vs, m, 64);
  if (l == 0) part2[w] = vs;
  __syncthreads();
  const float var = (part2[0] + part2[1] + part2[2] + part2[3]) * (1.f / 512.f);
  const float inv = rsqrtf(var);
  outb[base + c] = (bf16)(gamma[c] * (d0 * inv) + beta[c]);
  outb[base + c + 1] = (bf16)(gamma[c + 1] * (d1 * inv) + beta[c + 1]);
}

// ---------------- fused: sum 2 partials + bias + bf16 residual -> LN -> f32 out ----------------
__global__ __launch_bounds__(256) void add_ln2_k(
    const float* __restrict__ P,  // [2][4096][512]
    const bf16* __restrict__ rres, const float* __restrict__ bias,
    const float* __restrict__ gamma, const float* __restrict__ beta,
    float* __restrict__ outf) {
  const int row = blockIdx.x, tid = threadIdx.x;
  const size_t base = (size_t)row * 512;
  const float2 p0 = ((const float2*)(P + base))[tid];
  const float2 p1 = ((const float2*)(P + 2097152 + base))[tid];
  const int c = tid * 2;
  float s0 = p0.x + p1.x + bias[c] + (float)rres[base + c];
  float s1 = p0.y + p1.y + bias[c + 1] + (float)rres[base + c + 1];
  float sum = s0 + s1;
#pragma unroll
  for (int m = 1; m < 64; m <<= 1) sum += __shfl_xor(sum, m, 64);
  __shared__ float part[4], part2[4];
  const int w = tid >> 6, l = tid & 63;
  if (l == 0) part[w] = sum;
  __syncthreads();
  const float mean = (part[0] + part[1] + part[2] + part[3]) * (1.f / 512.f);
  const float d0 = s0 - mean, d1 = s1 - mean;
  float vs = d0 * d0 + d1 * d1;
#pragma unroll
  for (int m = 1; m < 64; m <<= 1) vs += __shfl_xor(vs, m, 64);
  if (l == 0) part2[w] = vs;
  __syncthreads();
  const float var = (part2[0] + part2[1] + part2[2] + part2[3]) * (1.f / 512.f);
  const float inv = rsqrtf(var);
  ((float2*)(outf + base))[tid] =
      make_float2(gamma[c] * (d0 * inv) + beta[c], gamma[c + 1] * (d1 * inv) + beta[c + 1]);
}

// ---------------- launch ----------------
extern "C" void kernel_launch(void* const* d_in, const int* in_sizes, int n_in,
                              void* d_out, int out_size, void* d_ws, size_t ws_size,
                              hipStream_t stream) {
  const float* x = (const float*)d_in[0];
  const float* wq = (const float*)d_in[1];
  const float* bq = (const float*)d_in[2];
  const float* wk = (const float*)d_in[3];
  const float* bk = (const float*)d_in[4];
  const float* wv = (const float*)d_in[5];
  const float* bv = (const float*)d_in[6];
  const float* wo = (const float*)d_in[7];
  const float* bo = (const float*)d_in[8];
  const float* g1 = (const float*)d_in[9];
  const float* be1 = (const float*)d_in[10];
  const float* w1 = (const float*)d_in[11];
  const float* b1 = (const float*)d_in[12];
  const float* w2 = (const float*)d_in[13];
  const float* b2 = (const float*)d_in[14];
  const float* g2 = (const float*)d_in[15];
  const float* be2 = (const float*)d_in[16];

  char* ws = (char*)d_ws;
  // layout (aliasing by liveness):
  bf16* xb    = (bf16*)(ws + 0);          // 4MB, cast -> QKV gemm
  bf16* y1b   = (bf16*)(ws + 0);          // 4MB, LN1 out -> FFN1 in, LN2 residual (aliases xb)
  bf16* wqkvT = (bf16*)(ws + 4194304);    // 1.5MB [1536][512]
  bf16* woT   = (bf16*)(ws + 5767168);    // 0.5MB
  bf16* w1T   = (bf16*)(ws + 6291456);    // 2MB
  bf16* w2T   = (bf16*)(ws + 8388608);    // 2MB
  float* cb   = (float*)(ws + 10485760);  // 8KB
  bf16* qkvb  = (bf16*)(ws + 10493952);   // 12MB [4096][1536], QKV -> attn
  float* t0   = (float*)(ws + 10493952);  // 16MB [2][4096][512] O-proj partials (alias qkvb, post-attn)
  bf16* f1    = (bf16*)(ws + 10493952);   // 16MB [4096][2048] FFN1 out (alias t0, post-LN1)
  bf16* vtb   = (bf16*)(ws + 23078656);   // 4MB [16][64][2048], vtrans -> attn
  bf16* yb    = (bf16*)(ws + 27272960);   // 4MB [4096][512], attn -> O-proj
  float* f2   = (float*)(ws + 27272960);  // 16MB [2][4096][512] FFN2 partials (alias yb, post-Oproj)

  cast_bf16_k<<<1024, 256, 0, stream>>>(x, xb, 262144);
  transpose_cast_k<<<512, 256, 0, stream>>>(wq, wqkvT, 8, 512, 64);
  transpose_cast_k<<<512, 256, 0, stream>>>(wk, wqkvT + 262144, 8, 512, 64);
  transpose_cast_k<<<512, 256, 0, stream>>>(wv, wqkvT + 524288, 8, 512, 64);
  transpose_cast_k<<<512, 256, 0, stream>>>(wo, woT, 1, 512, 512);
  transpose_cast_k<<<1024, 256, 0, stream>>>(w1, w1T, 1, 512, 2048);
  transpose_cast_k<<<1024, 256, 0, stream>>>(w2, w2T, 1, 2048, 512);
  build_cb_k<<<6, 256, 0, stream>>>(bq, bk, bv, cb);

  // QKV: 768 blocks
  gemmN64<2><<<dim3(32, 24, 1), 256, 0, stream>>>(xb, wqkvT, cb, nullptr, qkvb,
                                                  4096, 1536, 512, 512);
  vtrans_k<<<dim3(32, 16), 256, 0, stream>>>(qkvb, vtb);
  attn_fwd2<<<dim3(16, 16), 512, 0, stream>>>(qkvb, vtb, yb);
  // O-proj: split-K x2, 512 blocks, partials (bias added in LN1)
  gemmN64<0><<<dim3(32, 8, 2), 256, 0, stream>>>(yb, woT, nullptr, t0, nullptr,
                                                 4096, 512, 512, 256);
  add_ln1_k<<<4096, 256, 0, stream>>>(t0, x, bo, g1, be1, y1b);
  // FFN1: 1024 blocks
  gemmN64<1><<<dim3(32, 32, 1), 256, 0, stream>>>(y1b, w1T, b1, nullptr, f1,
                                                  4096, 2048, 512, 512);
  // FFN2: split-K x2, 512 blocks, partials (bias added in LN2)
  gemmN64<0><<<dim3(32, 8, 2), 256, 0, stream>>>(f1, w2T, nullptr, f2, nullptr,
                                                 4096, 512, 2048, 1024);
  add_ln2_k<<<4096, 256, 0, stream>>>(f2, y1b, b2, g2, be2, (float*)d_out);
}

// Round 5
// 113.363 us; speedup vs baseline: 1.7347x; 1.2594x over previous
//
#include <hip/hip_runtime.h>

typedef __bf16 bf16;
typedef __attribute__((ext_vector_type(8))) __bf16 bf16x8;
typedef __attribute__((ext_vector_type(4))) float f32x4;
typedef __attribute__((ext_vector_type(16))) float f32x16;

#define DEV __device__ __forceinline__

DEV f32x4 mfma16(bf16x8 a, bf16x8 b, f32x4 c) {
  return __builtin_amdgcn_mfma_f32_16x16x32_bf16(a, b, c, 0, 0, 0);
}
DEV f32x16 mfma32(bf16x8 a, bf16x8 b, f32x16 c) {
  return __builtin_amdgcn_mfma_f32_32x32x16_bf16(a, b, c, 0, 0, 0);
}
// async global->LDS, 16B/lane; LDS dest must be wave-linear (base + lane*16)
DEV void gll16(const bf16* g, bf16* l) {
  __builtin_amdgcn_global_load_lds(
      (const __attribute__((address_space(1))) void*)g,
      (__attribute__((address_space(3))) void*)l, 16, 0, 0);
}
DEV unsigned cvtpk(float a, float b) {
  unsigned r;
  asm("v_cvt_pk_bf16_f32 %0, %1, %2" : "=v"(r) : "v"(a), "v"(b));
  return r;
}
// v_permlane32_swap_b32 vdst, vsrc : vdst.hi(lanes>=32) <-> vsrc.lo(lanes<32)
DEV void pl32swap(unsigned& x, unsigned& y) {
  asm("v_permlane32_swap_b32 %0, %1" : "+v"(x), "+v"(y));
}

// ---------------- fused prep: x cast + all weight transposes + bias concat ----------------
// blocks [0,1024): xb cast (8 bf16/thread)
// blocks [1024,1792): 64x64 LDS-tiled transpose-cast (192 qkv + 64 wo + 256 w1 + 256 w2)
// block 1792: cb concat
__global__ __launch_bounds__(256) void prep_k(
    const float* __restrict__ x, const float* __restrict__ wq,
    const float* __restrict__ wk, const float* __restrict__ wv,
    const float* __restrict__ wo, const float* __restrict__ w1,
    const float* __restrict__ w2, const float* __restrict__ bq,
    const float* __restrict__ bk, const float* __restrict__ bv,
    bf16* __restrict__ xb, bf16* __restrict__ wqkvT, bf16* __restrict__ woT,
    bf16* __restrict__ w1T, bf16* __restrict__ w2T, float* __restrict__ cb) {
  const int blk = blockIdx.x, tid = threadIdx.x;
  if (blk < 1024) {  // x -> bf16, vectorized
    int i = blk * 256 + tid;
    const float4* p = (const float4*)x + (size_t)i * 2;
    float4 a = p[0], b = p[1];
    bf16x8 o;
    o[0] = (bf16)a.x; o[1] = (bf16)a.y; o[2] = (bf16)a.z; o[3] = (bf16)a.w;
    o[4] = (bf16)b.x; o[5] = (bf16)b.y; o[6] = (bf16)b.z; o[7] = (bf16)b.w;
    ((bf16x8*)xb)[i] = o;
    return;
  }
  if (blk == 1792) {  // bias concat
    for (int i = tid; i < 1536; i += 256)
      cb[i] = i < 512 ? bq[i] : (i < 1024 ? bk[i - 512] : bv[i - 1024]);
    return;
  }
  // ---- 64x64 transpose tile through padded LDS ----
  __shared__ float tile[64][65];
  const int t = blk - 1024;
  const float* src;
  bf16* dst;
  int C, Rout, r0, c0;
  if (t < 192) {  // wq/wk/wv per-head [512][64] -> [64][512]
    int mat = t / 64, rem = t % 64, head = rem >> 3, rt = rem & 7;
    src = (mat == 0 ? wq : mat == 1 ? wk : wv) + head * 32768;
    dst = wqkvT + (size_t)(mat * 8 + head) * 32768;
    C = 64; Rout = 512; r0 = rt * 64; c0 = 0;
  } else if (t < 256) {  // wo [512][512] -> [512][512]^T
    int t2 = t - 192;
    src = wo; dst = woT; C = 512; Rout = 512;
    r0 = (t2 >> 3) * 64; c0 = (t2 & 7) * 64;
  } else if (t < 512) {  // w1 [512][2048] -> [2048][512]
    int t2 = t - 256;
    src = w1; dst = w1T; C = 2048; Rout = 512;
    r0 = (t2 >> 5) * 64; c0 = (t2 & 31) * 64;
  } else {  // w2 [2048][512] -> [512][2048]
    int t2 = t - 512;
    src = w2; dst = w2T; C = 512; Rout = 2048;
    r0 = (t2 >> 3) * 64; c0 = (t2 & 7) * 64;
  }
#pragma unroll
  for (int j = 0; j < 4; ++j) {
    int e = j * 256 + tid;
    int r = e >> 4, c4 = e & 15;
    float4 f = *(const float4*)(src + (size_t)(r0 + r) * C + c0 + c4 * 4);
    tile[r][c4 * 4 + 0] = f.x;
    tile[r][c4 * 4 + 1] = f.y;
    tile[r][c4 * 4 + 2] = f.z;
    tile[r][c4 * 4 + 3] = f.w;
  }
  __syncthreads();
  const int co = tid >> 2, rr0 = (tid & 3) * 16;
  bf16x8 o0, o1;
#pragma unroll
  for (int k = 0; k < 8; ++k) o0[k] = (bf16)tile[rr0 + k][co];
#pragma unroll
  for (int k = 0; k < 8; ++k) o1[k] = (bf16)tile[rr0 + 8 + k][co];
  bf16* dp = dst + (size_t)(c0 + co) * Rout + r0 + rr0;
  *(bf16x8*)dp = o0;
  *(bf16x8*)(dp + 8) = o1;
}

// V^T extract: qkv [4096][1536] (V at col 1024+h*64) -> vtb [bh][64 dh][2048 s]
__global__ __launch_bounds__(256) void vtrans_k(const bf16* __restrict__ qkv,
                                                bf16* __restrict__ vtb) {
  __shared__ bf16 tile[64 * 68];
  const int tid = threadIdx.x;
  const int s0 = blockIdx.x * 64;
  const int bh = blockIdx.y, b = bh >> 3, hh = bh & 7;
  const bf16* src = qkv + 1024 + hh * 64;
#pragma unroll
  for (int j = 0; j < 2; ++j) {
    int slot = j * 256 + tid;
    int r = slot >> 3, cc = slot & 7;
    *(bf16x8*)(tile + r * 68 + cc * 8) =
        *(const bf16x8*)(src + (size_t)(b * 2048 + s0 + r) * 1536 + cc * 8);
  }
  __syncthreads();
  const int w = tid >> 6, lane = tid & 63;
#pragma unroll
  for (int sb2 = 0; sb2 < 2; ++sb2) {
    int sb = w * 2 + sb2;
    bf16x8 v;
#pragma unroll
    for (int jj = 0; jj < 8; ++jj) v[jj] = tile[(sb * 8 + jj) * 68 + lane];
    *(bf16x8*)(vtb + (size_t)bh * 131072 + (size_t)lane * 2048 + s0 + sb * 8) = v;
  }
}

// ---------------- 128x64 tile GEMM, optional split-K ----------------
// C[M][N] = A[M][K] * Bt[N][K]^T ; grid (M/128, N/64, nsplit), klen = K/nsplit
// EPI 0: f32 partial out (NO bias), slice z at outf + z*M*N
// EPI 1: bf16 relu(acc+bias)
// EPI 2: bf16 acc+bias, cols<512 scaled by 1/8 (QKV fused Q-scale)
template <int EPI>
__global__ __launch_bounds__(256) void gemmN64(
    const bf16* __restrict__ A, const bf16* __restrict__ Bt,
    const float* __restrict__ bias, float* __restrict__ outf,
    bf16* __restrict__ outb, int M, int N, int K, int klen) {
  __shared__ bf16 As[128 * 64];
  __shared__ bf16 Bs[64 * 64];
  const int tid = threadIdx.x;
  const int w = tid >> 6, l = tid & 63;
  const int lh = l & 15, lg = l >> 4;
  const int m0 = blockIdx.x * 128, n0 = blockIdx.y * 64;
  const int k0 = blockIdx.z * klen;
  const int mb = (w & 1) * 64, nb = (w >> 1) * 32;
  f32x4 acc[4][2] = {};
  for (int kt = k0; kt < k0 + klen; kt += 64) {
    __syncthreads();
#pragma unroll
    for (int j = 0; j < 4; ++j) {
      int slot = j * 256 + tid;
      int r = slot >> 3, cc = slot & 7;
      int kk = kt + ((cc ^ (r & 7)) << 3);  // swizzle SOURCE, LDS stays linear
      gll16(A + (size_t)(m0 + r) * K + kk, As + slot * 8);
    }
#pragma unroll
    for (int j = 0; j < 2; ++j) {
      int slot = j * 256 + tid;
      int r = slot >> 3, cc = slot & 7;
      int kk = kt + ((cc ^ (r & 7)) << 3);
      gll16(Bt + (size_t)(n0 + r) * K + kk, Bs + slot * 8);
    }
    __syncthreads();
#pragma unroll
    for (int kk = 0; kk < 2; ++kk) {
      bf16x8 af[4], bfr[2];
#pragma unroll
      for (int mi = 0; mi < 4; ++mi) {
        int r = mb + mi * 16 + lh;
        af[mi] = *(const bf16x8*)(As + r * 64 + (((kk * 4 + lg) ^ (r & 7)) << 3));
      }
#pragma unroll
      for (int ni = 0; ni < 2; ++ni) {
        int r = nb + ni * 16 + lh;
        bfr[ni] = *(const bf16x8*)(Bs + r * 64 + (((kk * 4 + lg) ^ (r & 7)) << 3));
      }
#pragma unroll
      for (int mi = 0; mi < 4; ++mi)
#pragma unroll
        for (int ni = 0; ni < 2; ++ni)
          acc[mi][ni] = mfma16(af[mi], bfr[ni], acc[mi][ni]);
    }
  }
  float* op = (EPI == 0) ? outf + (size_t)blockIdx.z * M * N : nullptr;
#pragma unroll
  for (int mi = 0; mi < 4; ++mi)
#pragma unroll
    for (int ni = 0; ni < 2; ++ni)
#pragma unroll
      for (int i = 0; i < 4; ++i) {
        int row = m0 + mb + mi * 16 + lg * 4 + i;  // C/D: col=lane&15, row=(lane>>4)*4+reg
        int col = n0 + nb + ni * 16 + lh;
        float v = acc[mi][ni][i];
        if (EPI == 0) {
          op[(size_t)row * N + col] = v;
        } else if (EPI == 1) {
          v += bias[col];
          outb[(size_t)row * N + col] = (bf16)fmaxf(v, 0.f);
        } else {
          v += bias[col];
          outb[(size_t)row * N + col] = (bf16)(col < 512 ? v * 0.125f : v);
        }
      }
}

// ---------------- flash attention fwd ----------------
// grid (16 qtiles, 16 bh); 8 waves. Waves 0-3: keys [0,1024), waves 4-7: [1024,2048),
// pair (w, w+4) shares q-rows qtile*128 + (w&3)*32 .. +32. 32x32x16 MFMA,
// swapped QK^T (S^T = K·Q^T), in-register softmax, P via cvt_pk+permlane32_swap.
__global__ __launch_bounds__(512) void attn_fwd2(
    const bf16* __restrict__ qkv,  // [4096][1536], Q pre-scaled by 1/8
    const bf16* __restrict__ vtb,  // [bh][64][2048]
    bf16* __restrict__ Y) {        // [4096][512]
  __shared__ __align__(16) char lds[65536];
  const int tid = threadIdx.x;
  const int w = tid >> 6, lane = tid & 63;
  const int l31 = lane & 31, h = lane >> 5;
  const int bh = blockIdx.y, b = bh >> 3, hh = bh & 7;
  const int qtile = blockIdx.x;
  const int half = w >> 2, wp = w & 3;
  const int q0 = qtile * 128 + wp * 32;
  const int tl = tid & 255, sh = tid >> 8;

  // Q B-frags: qf[g] = Q[q0+l31][g*16 + h*8 .. +8]
  bf16x8 qf[4];
  {
    const size_t rowQ = (size_t)(b * 2048 + q0 + l31) * 1536 + hh * 64;
#pragma unroll
    for (int g = 0; g < 4; ++g)
      qf[g] = *(const bf16x8*)(qkv + rowQ + g * 16 + h * 8);
  }
  const bf16* Kp = qkv + 512 + hh * 64;
  const bf16* Vp = vtb + (size_t)bh * 131072;

  f32x16 oacc[2] = {};
  float m_run = -1e30f, l_run = 0.f;

#define KBUF(d, hf) ((bf16*)(lds + (d) * 32768 + (hf) * 16384))
#define VBUF(d, hf) ((bf16*)(lds + (d) * 32768 + (hf) * 16384 + 8192))

  // stage iteration i into dbuf d (each half stages its own K,V^T 64x64 tiles)
  auto stage = [&](int i, int d) {
    const int k0 = sh * 1024 + i * 64;
#pragma unroll
    for (int j = 0; j < 2; ++j) {
      int slot = j * 256 + tl;
      int r = slot >> 3, cc = slot & 7;
      gll16(Kp + (size_t)(b * 2048 + k0 + r) * 1536 + ((cc ^ (r & 7)) << 3),
            KBUF(d, sh) + slot * 8);
      gll16(Vp + (size_t)r * 2048 + k0 + ((cc ^ (r & 7)) << 3),
            VBUF(d, sh) + slot * 8);
    }
  };

  stage(0, 0);
  __syncthreads();
  for (int i = 0; i < 16; ++i) {
    const int d = i & 1;
    if (i < 15) stage(i + 1, d ^ 1);
    const bf16* Kt = KBUF(d, half);
    const bf16* Vt = VBUF(d, half);
    // S^T tiles [32 keys x 32 q], keys kt*32 + (r&3)+8*(r>>2)+4h
    f32x16 st[2];
#pragma unroll
    for (int kt = 0; kt < 2; ++kt) {
      f32x16 z = {};
      const int r = kt * 32 + l31;
#pragma unroll
      for (int g = 0; g < 4; ++g) {
        bf16x8 kf = *(const bf16x8*)(Kt + r * 64 + (((2 * g + h) ^ (r & 7)) << 3));
        z = mfma32(kf, qf[g], z);
      }
      st[kt] = z;
    }
    // online softmax over 64 keys (32 regs/lane + cross-half)
    float mx = -1e30f;
#pragma unroll
    for (int kt = 0; kt < 2; ++kt)
#pragma unroll
      for (int r = 0; r < 16; ++r) mx = fmaxf(mx, st[kt][r]);
    mx = fmaxf(mx, __shfl_xor(mx, 32, 64));
    const float m_new = fmaxf(m_run, mx);
    const float scl = __expf(m_run - m_new);
    m_run = m_new;
    float ps = 0.f;
#pragma unroll
    for (int kt = 0; kt < 2; ++kt)
#pragma unroll
      for (int r = 0; r < 16; ++r) {
        float e = __expf(st[kt][r] - m_new);
        st[kt][r] = e;
        ps += e;
      }
    ps += __shfl_xor(ps, 32, 64);
    l_run = l_run * scl + ps;
    oacc[0] = oacc[0] * scl;
    oacc[1] = oacc[1] * scl;
    // pack P^T B-frags: per 16-key group, dwords {a0,a1,b0,b1}
    // pl32swap(a,b): a.hi <-> b.lo  =>  a: h0 keeps (0,1), h1 gets (8,9);
    //                                   b: h0 gets (4,5), h1 keeps (12,13).
    bf16x8 pf[4];
#pragma unroll
    for (int kt = 0; kt < 2; ++kt)
#pragma unroll
      for (int g = 0; g < 2; ++g) {
        unsigned a0 = cvtpk(st[kt][8 * g + 0], st[kt][8 * g + 1]);
        unsigned a1 = cvtpk(st[kt][8 * g + 2], st[kt][8 * g + 3]);
        unsigned b0 = cvtpk(st[kt][8 * g + 4], st[kt][8 * g + 5]);
        unsigned b1 = cvtpk(st[kt][8 * g + 6], st[kt][8 * g + 7]);
        pl32swap(a0, b0);
        pl32swap(a1, b1);
        union { unsigned u[4]; bf16x8 v; } pk;
        pk.u[0] = a0; pk.u[1] = a1; pk.u[2] = b0; pk.u[3] = b1;
        pf[kt * 2 + g] = pk.v;
      }
    // PV: Y^T[dh][q] += V^T frag x P frag
#pragma unroll
    for (int t = 0; t < 2; ++t) {
      const int r = t * 32 + l31;
#pragma unroll
      for (int kg = 0; kg < 4; ++kg) {
        bf16x8 vf = *(const bf16x8*)(Vt + r * 64 + (((2 * kg + h) ^ (r & 7)) << 3));
        oacc[t] = mfma32(vf, pf[kg], oacc[t]);
      }
    }
    __syncthreads();
  }

  // ---- merge split-KV halves ----
  // lds reuse: Ost [pair p][8 chunks][64 lanes][16B] @0 (32KB); m,l @32768 (2KB); Ytile @34816
  if (half == 1) {
    char* ob = lds + wp * 8192;
#pragma unroll
    for (int t = 0; t < 2; ++t)
#pragma unroll
      for (int c = 0; c < 4; ++c) {
        f32x4 v4 = {oacc[t][c * 4 + 0], oacc[t][c * 4 + 1],
                    oacc[t][c * 4 + 2], oacc[t][c * 4 + 3]};
        *(f32x4*)(ob + (t * 4 + c) * 1024 + lane * 16) = v4;
      }
    ((float2*)(lds + 32768))[wp * 64 + lane] = make_float2(m_run, l_run);
  }
  __syncthreads();
  bf16* Yt = (bf16*)(lds + 34816);  // [128 q][72 dh]
  if (half == 0) {
    float2 ml2 = ((const float2*)(lds + 32768))[wp * 64 + lane];
    const float mstar = fmaxf(m_run, ml2.x);
    const float e1 = __expf(m_run - mstar), e2 = __expf(ml2.x - mstar);
    const float lstar = l_run * e1 + ml2.y * e2;
    const float r1 = e1 / lstar, r2 = e2 / lstar;
    const char* ob = lds + wp * 8192;
#pragma unroll
    for (int t = 0; t < 2; ++t)
#pragma unroll
      for (int c = 0; c < 4; ++c) {
        f32x4 v4 = *(const f32x4*)(ob + (t * 4 + c) * 1024 + lane * 16);
#pragma unroll
        for (int j = 0; j < 4; ++j)
          oacc[t][c * 4 + j] = oacc[t][c * 4 + j] * r1 + v4[j] * r2;
      }
#pragma unroll
    for (int t = 0; t < 2; ++t)
#pragma unroll
      for (int r = 0; r < 16; ++r) {
        int dh = (r & 3) + 8 * (r >> 2) + 4 * h + 32 * t;
        Yt[(wp * 32 + l31) * 72 + dh] = (bf16)oacc[t][r];
      }
  }
  __syncthreads();
#pragma unroll
  for (int it = 0; it < 2; ++it) {
    int s = it * 512 + tid;
    int ql = s >> 3, cbk = s & 7;
    bf16x8 v = *(const bf16x8*)(Yt + ql * 72 + cbk * 8);
    *(bf16x8*)(Y + (size_t)(b * 2048 + qtile * 128 + ql) * 512 + hh * 64 + cbk * 8) = v;
  }
#undef KBUF
#undef VBUF
}

// ---------------- fused: sum 2 split-K partials + bias + f32 residual -> LN -> bf16 ----------------
__global__ __launch_bounds__(256) void add_ln1_k(
    const float* __restrict__ P,  // [2][4096][512]
    const float* __restrict__ xres, const float* __restrict__ bias,
    const float* __restrict__ gamma, const float* __restrict__ beta,
    bf16* __restrict__ outb) {
  const int row = blockIdx.x, tid = threadIdx.x;
  const size_t base = (size_t)row * 512;
  const float2 p0 = ((const float2*)(P + base))[tid];
  const float2 p1 = ((const float2*)(P + 2097152 + base))[tid];
  const float2 xr = ((const float2*)(xres + base))[tid];
  const int c = tid * 2;
  float s0 = p0.x + p1.x + bias[c] + xr.x;
  float s1 = p0.y + p1.y + bias[c + 1] + xr.y;
  float sum = s0 + s1;
#pragma unroll
  for (int m = 1; m < 64; m <<= 1) sum += __shfl_xor(sum, m, 64);
  __shared__ float part[4], part2[4];
  const int w = tid >> 6, l = tid & 63;
  if (l == 0) part[w] = sum;
  __syncthreads();
  const float mean = (part[0] + part[1] + part[2] + part[3]) * (1.f / 512.f);
  const float d0 = s0 - mean, d1 = s1 - mean;
  float vs = d0 * d0 + d1 * d1;
#pragma unroll
  for (int m = 1; m < 64; m <<= 1) vs += __shfl_xor(vs, m, 64);
  if (l == 0) part2[w] = vs;
  __syncthreads();
  const float var = (part2[0] + part2[1] + part2[2] + part2[3]) * (1.f / 512.f);
  const float inv = rsqrtf(var);
  outb[base + c] = (bf16)(gamma[c] * (d0 * inv) + beta[c]);
  outb[base + c + 1] = (bf16)(gamma[c + 1] * (d1 * inv) + beta[c + 1]);
}

// ---------------- fused: sum 2 partials + bias + bf16 residual -> LN -> f32 out ----------------
__global__ __launch_bounds__(256) void add_ln2_k(
    const float* __restrict__ P,  // [2][4096][512]
    const bf16* __restrict__ rres, const float* __restrict__ bias,
    const float* __restrict__ gamma, const float* __restrict__ beta,
    float* __restrict__ outf) {
  const int row = blockIdx.x, tid = threadIdx.x;
  const size_t base = (size_t)row * 512;
  const float2 p0 = ((const float2*)(P + base))[tid];
  const float2 p1 = ((const float2*)(P + 2097152 + base))[tid];
  const int c = tid * 2;
  float s0 = p0.x + p1.x + bias[c] + (float)rres[base + c];
  float s1 = p0.y + p1.y + bias[c + 1] + (float)rres[base + c + 1];
  float sum = s0 + s1;
#pragma unroll
  for (int m = 1; m < 64; m <<= 1) sum += __shfl_xor(sum, m, 64);
  __shared__ float part[4], part2[4];
  const int w = tid >> 6, l = tid & 63;
  if (l == 0) part[w] = sum;
  __syncthreads();
  const float mean = (part[0] + part[1] + part[2] + part[3]) * (1.f / 512.f);
  const float d0 = s0 - mean, d1 = s1 - mean;
  float vs = d0 * d0 + d1 * d1;
#pragma unroll
  for (int m = 1; m < 64; m <<= 1) vs += __shfl_xor(vs, m, 64);
  if (l == 0) part2[w] = vs;
  __syncthreads();
  const float var = (part2[0] + part2[1] + part2[2] + part2[3]) * (1.f / 512.f);
  const float inv = rsqrtf(var);
  ((float2*)(outf + base))[tid] =
      make_float2(gamma[c] * (d0 * inv) + beta[c], gamma[c + 1] * (d1 * inv) + beta[c + 1]);
}

// ---------------- launch ----------------
extern "C" void kernel_launch(void* const* d_in, const int* in_sizes, int n_in,
                              void* d_out, int out_size, void* d_ws, size_t ws_size,
                              hipStream_t stream) {
  const float* x = (const float*)d_in[0];
  const float* wq = (const float*)d_in[1];
  const float* bq = (const float*)d_in[2];
  const float* wk = (const float*)d_in[3];
  const float* bk = (const float*)d_in[4];
  const float* wv = (const float*)d_in[5];
  const float* bv = (const float*)d_in[6];
  const float* wo = (const float*)d_in[7];
  const float* bo = (const float*)d_in[8];
  const float* g1 = (const float*)d_in[9];
  const float* be1 = (const float*)d_in[10];
  const float* w1 = (const float*)d_in[11];
  const float* b1 = (const float*)d_in[12];
  const float* w2 = (const float*)d_in[13];
  const float* b2 = (const float*)d_in[14];
  const float* g2 = (const float*)d_in[15];
  const float* be2 = (const float*)d_in[16];

  char* ws = (char*)d_ws;
  // layout (aliasing by liveness):
  bf16* xb    = (bf16*)(ws + 0);          // 4MB, cast -> QKV gemm
  bf16* y1b   = (bf16*)(ws + 0);          // 4MB, LN1 out -> FFN1 in, LN2 residual (aliases xb)
  bf16* wqkvT = (bf16*)(ws + 4194304);    // 1.5MB [1536][512]
  bf16* woT   = (bf16*)(ws + 5767168);    // 0.5MB
  bf16* w1T   = (bf16*)(ws + 6291456);    // 2MB
  bf16* w2T   = (bf16*)(ws + 8388608);    // 2MB
  float* cb   = (float*)(ws + 10485760);  // 8KB
  bf16* qkvb  = (bf16*)(ws + 10493952);   // 12MB [4096][1536], QKV -> attn
  float* t0   = (float*)(ws + 10493952);  // 16MB [2][4096][512] O-proj partials (alias qkvb, post-attn)
  bf16* f1    = (bf16*)(ws + 10493952);   // 16MB [4096][2048] FFN1 out (alias t0, post-LN1)
  bf16* vtb   = (bf16*)(ws + 23078656);   // 4MB [16][64][2048], vtrans -> attn
  bf16* yb    = (bf16*)(ws + 27272960);   // 4MB [4096][512], attn -> O-proj
  float* f2   = (float*)(ws + 27272960);  // 16MB [2][4096][512] FFN2 partials (alias yb, post-Oproj)

  prep_k<<<1793, 256, 0, stream>>>(x, wq, wk, wv, wo, w1, w2, bq, bk, bv,
                                   xb, wqkvT, woT, w1T, w2T, cb);

  // QKV: 768 blocks
  gemmN64<2><<<dim3(32, 24, 1), 256, 0, stream>>>(xb, wqkvT, cb, nullptr, qkvb,
                                                  4096, 1536, 512, 512);
  vtrans_k<<<dim3(32, 16), 256, 0, stream>>>(qkvb, vtb);
  attn_fwd2<<<dim3(16, 16), 512, 0, stream>>>(qkvb, vtb, yb);
  // O-proj: split-K x2, 512 blocks, partials (bias added in LN1)
  gemmN64<0><<<dim3(32, 8, 2), 256, 0, stream>>>(yb, woT, nullptr, t0, nullptr,
                                                 4096, 512, 512, 256);
  add_ln1_k<<<4096, 256, 0, stream>>>(t0, x, bo, g1, be1, y1b);
  // FFN1: 1024 blocks
  gemmN64<1><<<dim3(32, 32, 1), 256, 0, stream>>>(y1b, w1T, b1, nullptr, f1,
                                                  4096, 2048, 512, 512);
  // FFN2: split-K x2, 512 blocks, partials (bias added in LN2)
  gemmN64<0><<<dim3(32, 8, 2), 256, 0, stream>>>(f1, w2T, nullptr, f2, nullptr,
                                                 4096, 512, 2048, 1024);
  add_ln2_k<<<4096, 256, 0, stream>>>(f2, y1b, b2, g2, be2, (float*)d_out);
}